// Round 1
// baseline (467.683 us; speedup 1.0000x reference)
//
#include <hip/hip_runtime.h>
#include <math.h>

#define C_DIM 2048
#define E_DIM 64
#define KC    128
#define TM    32     // tokens per block (K1)
#define TW    8      // tokens per wave (K1)

// ---------------- K1: logits (fp64-accurate) + top-2 + softmax ----------------
// lane = expert. Per-wave tokens are wave-uniform, so x is read via SCALAR loads
// (s_load -> SGPR, broadcast for free as the FMA scalar operand). Only w lives in
// LDS (lane-varying reads). fp32 sub-dots of 16 dims (sequential fmaf chain, fixed
// order) are accumulated in fp64: deviation ~3e-7 absolute, far below the fp32
// reference's own ~1e-5 accumulation error, so top-2 ordering matches.
__launch_bounds__(256)
__global__ void k_logits_top2(const float* __restrict__ x, const float* __restrict__ w,
                              int* __restrict__ idx0, int* __restrict__ idx1,
                              float* __restrict__ probs, int N)
{
    __shared__ float wsh[E_DIM][KC + 4];    // 33 KB, +4 pad keeps b128 reads conflict-free

    const int tid  = threadIdx.x;
    const int lane = tid & 63;
    // readfirstlane: provably wave-uniform wave id -> x addresses become scalar
    const int wid  = __builtin_amdgcn_readfirstlane(tid >> 6);
    const int t0   = blockIdx.x * TM;
    const int tw   = wid * TW;

    double acc[TW];
#pragma unroll
    for (int t = 0; t < TW; ++t) acc[t] = 0.0;

    for (int kb = 0; kb < C_DIM; kb += KC) {
        __syncthreads();
        // stage w tile [64][128]: 2048 float4, 8 per thread
#pragma unroll
        for (int r = 0; r < 8; ++r) {
            int i = tid + 256 * r;
            int row = i >> 5;
            int col = i & 31;
            float4 v = *(const float4*)(w + (size_t)row * C_DIM + kb + col * 4);
            *(float4*)(&wsh[row][col * 4]) = v;
        }
        __syncthreads();

        for (int kk = 0; kk < KC; kk += 16) {
            // w fragment for this lane's expert: 16 floats via 4 x ds_read_b128
            float wf[16];
#pragma unroll
            for (int j = 0; j < 4; ++j) {
                float4 v = *(const float4*)(&wsh[lane][kk + 4 * j]);
                wf[4 * j + 0] = v.x; wf[4 * j + 1] = v.y;
                wf[4 * j + 2] = v.z; wf[4 * j + 3] = v.w;
            }
#pragma unroll
            for (int t = 0; t < TW; ++t) {
                // wave-uniform address -> scalar loads (s_load_dwordx4)
                const float4* xp = (const float4*)(x + (size_t)(t0 + tw + t) * C_DIM + kb + kk);
                float4 xa = xp[0], xb = xp[1], xc = xp[2], xd = xp[3];
                // fixed-order 16-element fp32 chain, then one fp64 accumulate
                float s = xa.x * wf[0];
                s = fmaf(xa.y, wf[1],  s); s = fmaf(xa.z, wf[2],  s); s = fmaf(xa.w, wf[3],  s);
                s = fmaf(xb.x, wf[4],  s); s = fmaf(xb.y, wf[5],  s); s = fmaf(xb.z, wf[6],  s);
                s = fmaf(xb.w, wf[7],  s); s = fmaf(xc.x, wf[8],  s); s = fmaf(xc.y, wf[9],  s);
                s = fmaf(xc.z, wf[10], s); s = fmaf(xc.w, wf[11], s); s = fmaf(xd.x, wf[12], s);
                s = fmaf(xd.y, wf[13], s); s = fmaf(xd.z, wf[14], s); s = fmaf(xd.w, wf[15], s);
                acc[t] += (double)s;
            }
        }
    }

    // per-token top-2 across the 64 lanes (lane == expert). Lower index wins ties
    // (matches jax.lax.top_k).
#pragma unroll
    for (int t = 0; t < TW; ++t) {
        double v = acc[t];
        int ix = lane;
#pragma unroll
        for (int off = 32; off > 0; off >>= 1) {
            double ov = __shfl_down(v, off, 64);
            int    oi = __shfl_down(ix, off, 64);
            if (ov > v || (ov == v && oi < ix)) { v = ov; ix = oi; }
        }
        int    i1 = __shfl(ix, 0, 64);
        double v1 = __shfl(v, 0, 64);

        v  = (lane == i1) ? -1e300 : acc[t];
        ix = lane;
#pragma unroll
        for (int off = 32; off > 0; off >>= 1) {
            double ov = __shfl_down(v, off, 64);
            int    oi = __shfl_down(ix, off, 64);
            if (ov > v || (ov == v && oi < ix)) { v = ov; ix = oi; }
        }
        int    i2 = __shfl(ix, 0, 64);
        double v2 = __shfl(v, 0, 64);

        if (lane == 0) {
            int n = t0 + tw + t;
            double p0 = 1.0 / (1.0 + exp(v2 - v1));   // stable: v2 <= v1
            idx0[n] = i1;
            idx1[n] = i2;
            probs[2 * n]     = (float)p0;
            probs[2 * n + 1] = (float)(1.0 - p0);
        }
    }
}

// ---------------- K2: per-expert deterministic rank scan (barrier-free) ----------------
// One wave per expert: ballot + popcount running scan in k-major token order.
// No __syncthreads; 16 independent loads in flight per step.
__launch_bounds__(64)
__global__ void k_scan(const int* __restrict__ idx0, const int* __restrict__ idx1,
                       int* __restrict__ r0, int* __restrict__ r1, int N)
{
    const int e    = blockIdx.x;
    const int lane = threadIdx.x;
    const unsigned long long ltmask = (1ull << lane) - 1ull;

    int running = 0;   // wave-uniform (ballot result is uniform)
#pragma unroll
    for (int pass = 0; pass < 2; ++pass) {
        const int* __restrict__ idx = pass ? idx1 : idx0;
        int*       __restrict__ r   = pass ? r1   : r0;
        for (int base = 0; base < N; base += 64 * 16) {
            int v[16];
#pragma unroll
            for (int j = 0; j < 16; ++j) v[j] = idx[base + j * 64 + lane];
#pragma unroll
            for (int j = 0; j < 16; ++j) {
                bool p = (v[j] == e);
                unsigned long long b = __ballot(p);
                if (p) r[base + j * 64 + lane] = running + __popcll(b & ltmask);
                running += __popcll(b);
            }
        }
    }
}

// ---------------- K3: one-hot capacity mask fill + tail outputs (merged) ----------------
__launch_bounds__(256)
__global__ void k_mask_tail(const int* __restrict__ idx0, const int* __restrict__ idx1,
                            const int* __restrict__ r0, const int* __restrict__ r1,
                            const float* __restrict__ probs,
                            float* __restrict__ out, int N, int cap)
{
    int f = blockIdx.x * blockDim.x + threadIdx.x;   // float4 index, total N*32
    int n   = f >> 5;
    int rem = (f & 31) * 4;       // 0..124 within the token's 128 floats
    int k   = rem >> 6;           // 0 or 1
    int e0  = rem & 63;           // first of 4 experts this f4 covers
    int ix = k ? idx1[n] : idx0[n];
    int rr = k ? r1[n]   : r0[n];
    float val = (rr < cap) ? 1.0f : 0.0f;
    float4 o = make_float4(0.f, 0.f, 0.f, 0.f);
    int d = ix - e0;
    if (d >= 0 && d < 4) ((float*)&o)[d] = val;
    *(float4*)(out + (size_t)f * 4) = o;

    // tail: probs_masked / indices / final_rank / capacity
    size_t base = (size_t)2 * N * E_DIM;
    if (f < 2 * N) {
        int n2  = f >> 1;
        int k2  = f & 1;
        int ix2 = k2 ? idx1[n2] : idx0[n2];
        int rr2 = k2 ? r1[n2]   : r0[n2];
        float p = probs[f];
        bool keep = (rr2 < cap);
        out[base + f]         = keep ? p : 0.0f;   // router_probs_masked
        out[base + 2 * N + f] = (float)ix2;        // top_k_indices
        out[base + 4 * N + f] = (float)rr2;        // final_rank
    }
    if (f == 0) out[base + 6 * N] = (float)cap;    // exp_capacity
}

extern "C" void kernel_launch(void* const* d_in, const int* in_sizes, int n_in,
                              void* d_out, int out_size, void* d_ws, size_t ws_size,
                              hipStream_t stream)
{
    const float* x  = (const float*)d_in[0];
    const float* wg = (const float*)d_in[1];
    const int N = in_sizes[0] / C_DIM;   // 16384 tokens

    // workspace layout (24*N bytes total = 384 KB)
    char* ws = (char*)d_ws;
    int*   idx0  = (int*)ws;
    int*   idx1  = idx0 + N;
    float* probs = (float*)(idx1 + N);
    int*   r0    = (int*)(probs + 2 * N);
    int*   r1    = r0 + N;

    float* out = (float*)d_out;

    int cap = (int)((long long)2 * 2 * N / E_DIM);   // TOP_K * EVAL_CAPACITY * N / E
    if (cap < 4) cap = 4;

    k_logits_top2<<<N / TM, 256, 0, stream>>>(x, wg, idx0, idx1, probs, N);
    k_scan<<<E_DIM, 64, 0, stream>>>(idx0, idx1, r0, r1, N);
    k_mask_tail<<<(N * 32) / 256, 256, 0, stream>>>(idx0, idx1, r0, r1, probs, out, N, cap);
}

// Round 2
// 311.208 us; speedup vs baseline: 1.5028x; 1.5028x over previous
//
#include <hip/hip_runtime.h>
#include <math.h>

#define C_DIM 2048
#define E_DIM 64
#define KC    128     // K-chunk staged in LDS
#define BT    64      // tokens per block in K1 (grid = N/BT = 256 blocks -> 1/CU)

// ---------------- K1: logits GEMM (Mr=4 x Nr=4 register tile) + top-2 + softmax + histogram ----
// Block computes a 64-token x 64-expert tile. Thread (r=tid>>4, c=tid&15) owns
// tokens 4r..4r+3 and experts 4c..4c+3. Per 4-dim k-step: 8 ds_read_b128 feed
// 256 lane-FMAs (vs 9 reads / 32 FMAs in the old lane=expert scheme).
// fp32 accumulation in fixed order over 16-dim chunks, flushed to fp64 (same
// numeric recipe that passed in earlier rounds).
__launch_bounds__(256)
__global__ void k_logits_top2(const float* __restrict__ x, const float* __restrict__ w,
                              int* __restrict__ idx0, int* __restrict__ idx1,
                              float* __restrict__ probs, int* __restrict__ gcounts, int N)
{
    __shared__ float xs[BT][KC + 4];     // +4 pad: wave's 4 distinct rows land 2-way (free)
    __shared__ float wsh[E_DIM * KC];    // XOR-swizzled on (row>>2)&7: 16 distinct rows -> 2-way

    const int tid = threadIdx.x;
    const int c   = tid & 15;            // expert group: experts 4c..4c+3
    const int r   = tid >> 4;            // token group:  tokens 4r..4r+3
    const int t0  = blockIdx.x * BT;
    const int swz = (c & 7) << 2;        // read-side swizzle (row>>2 == c for our 4 experts)

    double acc[4][4];
#pragma unroll
    for (int i = 0; i < 4; ++i)
#pragma unroll
        for (int j = 0; j < 4; ++j) acc[i][j] = 0.0;

    for (int kb = 0; kb < C_DIM; kb += KC) {
        __syncthreads();
        // stage x tile: 64 rows x 128 floats = 2048 float4, 8/thread, coalesced
#pragma unroll
        for (int rep = 0; rep < 8; ++rep) {
            int i = tid + 256 * rep;
            int row = i >> 5;
            int col = (i & 31) * 4;
            float4 v = *(const float4*)(x + (size_t)(t0 + row) * C_DIM + kb + col);
            *(float4*)(&xs[row][col]) = v;
        }
        // stage w tile with XOR swizzle keyed on (row>>2)&7 (bits 2..4 of dword col)
#pragma unroll
        for (int rep = 0; rep < 8; ++rep) {
            int i = tid + 256 * rep;
            int row = i >> 5;
            int col = (i & 31) * 4;
            float4 v = *(const float4*)(w + (size_t)row * C_DIM + kb + col);
            int scol = col ^ (((row >> 2) & 7) << 2);
            *(float4*)(&wsh[row * KC + scol]) = v;
        }
        __syncthreads();

        for (int k8 = 0; k8 < KC; k8 += 16) {
            float sc[4][4];
#pragma unroll
            for (int i = 0; i < 4; ++i)
#pragma unroll
                for (int j = 0; j < 4; ++j) sc[i][j] = 0.0f;
#pragma unroll
            for (int k = 0; k < 16; k += 4) {
                float4 xv[4], wv[4];
#pragma unroll
                for (int i = 0; i < 4; ++i)
                    xv[i] = *(const float4*)(&xs[4 * r + i][k8 + k]);
#pragma unroll
                for (int j = 0; j < 4; ++j)
                    wv[j] = *(const float4*)(&wsh[(4 * c + j) * KC + ((k8 + k) ^ swz)]);
#pragma unroll
                for (int i = 0; i < 4; ++i)
#pragma unroll
                    for (int j = 0; j < 4; ++j) {
                        sc[i][j] = fmaf(xv[i].x, wv[j].x, sc[i][j]);
                        sc[i][j] = fmaf(xv[i].y, wv[j].y, sc[i][j]);
                        sc[i][j] = fmaf(xv[i].z, wv[j].z, sc[i][j]);
                        sc[i][j] = fmaf(xv[i].w, wv[j].w, sc[i][j]);
                    }
            }
#pragma unroll
            for (int i = 0; i < 4; ++i)
#pragma unroll
                for (int j = 0; j < 4; ++j) acc[i][j] += (double)sc[i][j];
        }
    }

    // repurpose wsh as the block histogram (counts[2][64])
    __syncthreads();
    int* cnt = (int*)wsh;
    if (tid < 128) cnt[tid] = 0;
    __syncthreads();

    // per-token top-2: local top-2 of this thread's 4 experts, then width-16
    // shuffle merge across the token group's 16 lanes. Lower index wins ties
    // (matches jax.lax.top_k; all comparisons on fp64 accumulators).
#pragma unroll
    for (int i = 0; i < 4; ++i) {
        double v1 = acc[i][0]; int i1 = 4 * c;
        double v2 = -1e300;    int i2 = 0;
#pragma unroll
        for (int j = 1; j < 4; ++j) {
            double v = acc[i][j]; int e = 4 * c + j;
            if (v > v1)      { v2 = v1; i2 = i1; v1 = v; i1 = e; }
            else if (v > v2) { v2 = v;  i2 = e; }
        }
#pragma unroll
        for (int off = 8; off > 0; off >>= 1) {
            double b1 = __shfl_down(v1, off, 16); int bi1 = __shfl_down(i1, off, 16);
            double b2 = __shfl_down(v2, off, 16); int bi2 = __shfl_down(i2, off, 16);
            bool bwin = (b1 > v1) || (b1 == v1 && bi1 < i1);
            double n1 = bwin ? b1 : v1; int ni1 = bwin ? bi1 : i1;
            double ca = bwin ? v1 : b1; int cia = bwin ? i1  : bi1;  // loser of firsts
            double cb = bwin ? b2 : v2; int cib = bwin ? bi2 : i2;   // winner's second
            bool s2 = (cb > ca) || (cb == ca && cib < cia);
            v1 = n1; i1 = ni1;
            v2 = s2 ? cb : ca; i2 = s2 ? cib : cia;
        }
        if (c == 0) {
            int n = t0 + 4 * r + i;
            double p0 = 1.0 / (1.0 + exp(v2 - v1));   // stable: v2 <= v1
            idx0[n] = i1;
            idx1[n] = i2;
            probs[2 * n]     = (float)p0;
            probs[2 * n + 1] = (float)(1.0 - p0);
            atomicAdd(&cnt[i1], 1);
            atomicAdd(&cnt[64 + i2], 1);
        }
    }

    __syncthreads();
    // segment id s = k*nblk + block  (k-major == rank order)
    if (tid < 128) {
        int k = tid >> 6, e = tid & 63;
        gcounts[((size_t)k * gridDim.x + blockIdx.x) * 64 + e] = cnt[tid];
    }
}

// ---------------- K2: ranks (cross-segment prefix + intra-segment ballot) + mask + tail ----
__launch_bounds__(128)
__global__ void k_rank_out(const int* __restrict__ idx0, const int* __restrict__ idx1,
                           const int* __restrict__ gcounts, const float* __restrict__ probs,
                           float* __restrict__ out, int N, int cap, int nblk)
{
    const int b = blockIdx.x, tid = threadIdx.x;
    const int lane = tid & 63, kk = tid >> 6;   // wave 0: k=0, wave 1: k=1
    const int t0 = b * 64;
    __shared__ int sm_ix[2][64], sm_rk[2][64];

    const int v = (kk ? idx1 : idx0)[t0 + lane];

    // cross-segment base: counts of expert v in all earlier segments (deterministic)
    int base = 0;
    const int slim = kk * nblk + b;
    int s = 0;
    for (; s + 4 <= slim; s += 4)
        base += gcounts[(s + 0) * 64 + v] + gcounts[(s + 1) * 64 + v]
              + gcounts[(s + 2) * 64 + v] + gcounts[(s + 3) * 64 + v];
    for (; s < slim; ++s) base += gcounts[s * 64 + v];

    // intra-segment prefix via per-expert ballots (lane order == token order)
    const unsigned long long ltm = (1ull << lane) - 1ull;
    int pre = 0;
    for (int e = 0; e < 64; ++e) {
        unsigned long long bb = __ballot(v == e);
        if (v == e) pre = __popcll(bb & ltm);
    }
    const int rk = base + pre;
    sm_ix[kk][lane] = v;
    sm_rk[kk][lane] = rk;
    __syncthreads();

    // one-hot capacity mask rows for these 64 tokens: 2048 float4, 16/thread
#pragma unroll
    for (int rep = 0; rep < 16; ++rep) {
        int f   = tid + 128 * rep;
        int n2  = f >> 5;
        int rem = (f & 31) * 4;      // 0..124 within the token's 128 floats
        int kq  = rem >> 6;
        int e0  = rem & 63;
        int ix  = sm_ix[kq][n2];
        int rr  = sm_rk[kq][n2];
        float val = (rr < cap) ? 1.0f : 0.0f;
        float4 o = make_float4(0.f, 0.f, 0.f, 0.f);
        int d = ix - e0;
        if (d >= 0 && d < 4) ((float*)&o)[d] = val;
        *(float4*)(out + (size_t)(t0 + n2) * 128 + rem) = o;
    }

    // tail: probs_masked / indices / final_rank / capacity
    size_t B = (size_t)2 * N * E_DIM;
    {
        int n2 = tid >> 1, kq = tid & 1;
        int gi = 2 * (t0 + n2) + kq;
        int ix = sm_ix[kq][n2];
        int rr = sm_rk[kq][n2];
        bool keep = rr < cap;
        out[B + gi]         = keep ? probs[gi] : 0.0f;
        out[B + 2 * N + gi] = (float)ix;
        out[B + 4 * N + gi] = (float)rr;
    }
    if (b == 0 && tid == 0) out[B + 6 * N] = (float)cap;
}

extern "C" void kernel_launch(void* const* d_in, const int* in_sizes, int n_in,
                              void* d_out, int out_size, void* d_ws, size_t ws_size,
                              hipStream_t stream)
{
    const float* x  = (const float*)d_in[0];
    const float* wg = (const float*)d_in[1];
    const int N = in_sizes[0] / C_DIM;   // 16384 tokens
    const int nblk = N / BT;             // 256

    // workspace: idx0[N] idx1[N] probs[2N] gcounts[2*nblk*64]  = 384 KB
    char* ws = (char*)d_ws;
    int*   idx0    = (int*)ws;
    int*   idx1    = idx0 + N;
    float* probs   = (float*)(idx1 + N);
    int*   gcounts = (int*)(probs + 2 * N);

    float* out = (float*)d_out;

    int cap = (int)((long long)2 * 2 * N / E_DIM);   // TOP_K * EVAL_CAPACITY * N / E
    if (cap < 4) cap = 4;

    k_logits_top2<<<nblk, 256, 0, stream>>>(x, wg, idx0, idx1, probs, gcounts, N);
    k_rank_out<<<nblk, 128, 0, stream>>>(idx0, idx1, gcounts, probs, out, N, cap, nblk);
}

// Round 3
// 273.412 us; speedup vs baseline: 1.7105x; 1.1382x over previous
//
#include <hip/hip_runtime.h>
#include <math.h>

#define C_DIM 2048
#define E_DIM 64
#define KC    128      // K dims per LDS chunk
#define BT    64       // tokens per block

typedef _Float16 h4    __attribute__((ext_vector_type(4)));
typedef _Float16 v8hf  __attribute__((ext_vector_type(8)));
typedef float    f32x4 __attribute__((ext_vector_type(4)));

#define SCALE      64.0f
#define INV_SCALE2 (1.0f/4096.0f)

// ---------------- K0: pre-split w into exact f16 (hi, lo) pairs, scaled x64 ----------------
// w*64 = wh + wl exactly up to 2^-22 rel (h=RNE f16, r=s-(float)h exact, l=RNE f16(r)).
__launch_bounds__(256)
__global__ void k_wsplit(const float* __restrict__ w, _Float16* __restrict__ wh,
                         _Float16* __restrict__ wl)
{
    int i = blockIdx.x * blockDim.x + threadIdx.x;      // float4 index, 32768 total
    float4 v = ((const float4*)w)[i];
    float s0 = v.x * SCALE, s1 = v.y * SCALE, s2 = v.z * SCALE, s3 = v.w * SCALE;
    _Float16 h0 = (_Float16)s0, h1 = (_Float16)s1, h2 = (_Float16)s2, h3 = (_Float16)s3;
    h4 hv = {h0, h1, h2, h3};
    h4 lv = {(_Float16)(s0 - (float)h0), (_Float16)(s1 - (float)h1),
             (_Float16)(s2 - (float)h2), (_Float16)(s3 - (float)h3)};
    ((h4*)wh)[i] = hv;
    ((h4*)wl)[i] = lv;
}

// swizzled frag read: tile is [64][KC] f16, byte offset XOR'd by (row&7)<<4
__device__ __forceinline__ v8hf frag(const _Float16* tile, int row, int kbyte)
{
    const char* p = (const char*)(tile + row * KC);
    return *(const v8hf*)(p + (kbyte ^ ((row & 7) << 4)));
}

// ---------------- K1: MFMA logits (fp32 via f16 2-split, 3 products) + top-2 + histogram ----
// Block: 64 tokens x 64 experts. 4 waves in 2x2 grid: wave (wm,wn) owns
// tokens 32wm..+31, experts 32wn..+31 as 2x2 16x16x32 MFMA tiles.
// acc1 accumulates hh (big terms), acc2 accumulates hl+lh (2^-12-scale terms):
// logit = (acc1+acc2)/4096, abs error ~1e-6 (>=100x below min top-2 gap).
__launch_bounds__(256)
__global__ void k_logits_top2(const float* __restrict__ x,
                              const _Float16* __restrict__ whg, const _Float16* __restrict__ wlg,
                              int* __restrict__ idx0, int* __restrict__ idx1,
                              float* __restrict__ probs, int* __restrict__ gcounts, int N)
{
    __shared__ _Float16 xh_s[2][BT][KC];     // 16 KB x2
    __shared__ _Float16 xl_s[2][BT][KC];
    __shared__ _Float16 wh_s[2][E_DIM][KC];
    __shared__ _Float16 wl_s[2][E_DIM][KC];
    __shared__ float    lgs[BT][E_DIM + 1];  // 16.6 KB, +1 pad
    __shared__ int      cnt[128];

    const int tid  = threadIdx.x;
    const int lane = tid & 63;
    const int wid  = tid >> 6;
    const int wm   = wid >> 1, wn = wid & 1;
    const int ln15 = lane & 15;
    const int kg16 = (lane >> 4) * 16;
    const int t0   = blockIdx.x * BT;

    if (tid < 128) cnt[tid] = 0;

    f32x4 acc1[2][2], acc2[2][2];
#pragma unroll
    for (int mi = 0; mi < 2; ++mi)
#pragma unroll
        for (int ni = 0; ni < 2; ++ni) { acc1[mi][ni] = (f32x4)0.0f; acc2[mi][ni] = (f32x4)0.0f; }

    float4 xr[8], wr[8];

    // ---- stage chunk 0 into buffer 0
    {
        const int kb = 0;
#pragma unroll
        for (int rep = 0; rep < 8; ++rep) {
            int i = tid + 256 * rep;
            int row = i >> 5, c4 = i & 31;
            xr[rep] = *(const float4*)(x + (size_t)(t0 + row) * C_DIM + kb + c4 * 4);
        }
#pragma unroll
        for (int rep = 0; rep < 8; ++rep) {
            int i = tid + 256 * (rep & 3);
            int row = i >> 4, u = i & 15;
            const _Float16* src = (rep < 4) ? whg : wlg;
            wr[rep] = *(const float4*)((const char*)src + ((size_t)row * C_DIM + kb) * 2 + u * 16);
        }
#pragma unroll
        for (int rep = 0; rep < 8; ++rep) {
            int i = tid + 256 * rep;
            int row = i >> 5, c4 = i & 31;
            float4 v = xr[rep];
            float s0 = v.x * SCALE, s1 = v.y * SCALE, s2 = v.z * SCALE, s3 = v.w * SCALE;
            _Float16 h0 = (_Float16)s0, h1 = (_Float16)s1, h2 = (_Float16)s2, h3 = (_Float16)s3;
            h4 hv = {h0, h1, h2, h3};
            h4 lv = {(_Float16)(s0 - (float)h0), (_Float16)(s1 - (float)h1),
                     (_Float16)(s2 - (float)h2), (_Float16)(s3 - (float)h3)};
            int boff = (c4 * 8) ^ ((row & 7) << 4);
            *(h4*)((char*)&xh_s[0][row][0] + boff) = hv;
            *(h4*)((char*)&xl_s[0][row][0] + boff) = lv;
        }
#pragma unroll
        for (int rep = 0; rep < 8; ++rep) {
            int i = tid + 256 * (rep & 3);
            int row = i >> 4, u = i & 15;
            int boff = (u * 16) ^ ((row & 7) << 4);
            _Float16* dst = (rep < 4) ? &wh_s[0][0][0] : &wl_s[0][0][0];
            *(float4*)((char*)(dst + row * KC) + boff) = wr[rep];
        }
    }
    __syncthreads();

    // ---- main loop: 16 chunks, double-buffered; prefetch loads issued before MFMA (T14)
    for (int c = 0; c < 16; ++c) {
        const int b  = c & 1;
        const int nb = b ^ 1;
        if (c < 15) {
            const int kb = (c + 1) * KC;
#pragma unroll
            for (int rep = 0; rep < 8; ++rep) {
                int i = tid + 256 * rep;
                int row = i >> 5, c4 = i & 31;
                xr[rep] = *(const float4*)(x + (size_t)(t0 + row) * C_DIM + kb + c4 * 4);
            }
#pragma unroll
            for (int rep = 0; rep < 8; ++rep) {
                int i = tid + 256 * (rep & 3);
                int row = i >> 4, u = i & 15;
                const _Float16* src = (rep < 4) ? whg : wlg;
                wr[rep] = *(const float4*)((const char*)src + ((size_t)row * C_DIM + kb) * 2 + u * 16);
            }
        }

        // MFMA over current buffer: 4 K32 steps x 12 MFMAs
#pragma unroll
        for (int kk = 0; kk < 4; ++kk) {
            const int kbyte = kk * 64 + kg16;
            v8hf ah[2], al[2], bh[2], bl[2];
#pragma unroll
            for (int mi = 0; mi < 2; ++mi) {
                int row = 32 * wm + 16 * mi + ln15;
                ah[mi] = frag(&xh_s[b][0][0], row, kbyte);
                al[mi] = frag(&xl_s[b][0][0], row, kbyte);
            }
#pragma unroll
            for (int ni = 0; ni < 2; ++ni) {
                int er = 32 * wn + 16 * ni + ln15;
                bh[ni] = frag(&wh_s[b][0][0], er, kbyte);
                bl[ni] = frag(&wl_s[b][0][0], er, kbyte);
            }
#pragma unroll
            for (int mi = 0; mi < 2; ++mi)
#pragma unroll
                for (int ni = 0; ni < 2; ++ni) {
                    acc1[mi][ni] = __builtin_amdgcn_mfma_f32_16x16x32_f16(ah[mi], bh[ni], acc1[mi][ni], 0, 0, 0);
                    acc2[mi][ni] = __builtin_amdgcn_mfma_f32_16x16x32_f16(ah[mi], bl[ni], acc2[mi][ni], 0, 0, 0);
                    acc2[mi][ni] = __builtin_amdgcn_mfma_f32_16x16x32_f16(al[mi], bh[ni], acc2[mi][ni], 0, 0, 0);
                }
        }

        if (c < 15) {
            // convert + write next chunk into the other buffer
#pragma unroll
            for (int rep = 0; rep < 8; ++rep) {
                int i = tid + 256 * rep;
                int row = i >> 5, c4 = i & 31;
                float4 v = xr[rep];
                float s0 = v.x * SCALE, s1 = v.y * SCALE, s2 = v.z * SCALE, s3 = v.w * SCALE;
                _Float16 h0 = (_Float16)s0, h1 = (_Float16)s1, h2 = (_Float16)s2, h3 = (_Float16)s3;
                h4 hv = {h0, h1, h2, h3};
                h4 lv = {(_Float16)(s0 - (float)h0), (_Float16)(s1 - (float)h1),
                         (_Float16)(s2 - (float)h2), (_Float16)(s3 - (float)h3)};
                int boff = (c4 * 8) ^ ((row & 7) << 4);
                *(h4*)((char*)&xh_s[nb][row][0] + boff) = hv;
                *(h4*)((char*)&xl_s[nb][row][0] + boff) = lv;
            }
#pragma unroll
            for (int rep = 0; rep < 8; ++rep) {
                int i = tid + 256 * (rep & 3);
                int row = i >> 4, u = i & 15;
                int boff = (u * 16) ^ ((row & 7) << 4);
                _Float16* dst = (rep < 4) ? &wh_s[nb][0][0] : &wl_s[nb][0][0];
                *(float4*)((char*)(dst + row * KC) + boff) = wr[rep];
            }
        }
        __syncthreads();
    }

    // ---- logits to LDS (C/D map: row=(lane>>4)*4+reg, col=lane&15)
#pragma unroll
    for (int mi = 0; mi < 2; ++mi)
#pragma unroll
        for (int ni = 0; ni < 2; ++ni) {
            f32x4 s = acc1[mi][ni];
            f32x4 t = acc2[mi][ni];
#pragma unroll
            for (int g = 0; g < 4; ++g) {
                int row = 32 * wm + 16 * mi + ((lane >> 4) << 2) + g;
                int col = 32 * wn + 16 * ni + ln15;
                lgs[row][col] = (s[g] + t[g]) * INV_SCALE2;
            }
        }
    __syncthreads();

    // ---- per-token top-2 (lane == expert), lower index wins ties (matches lax.top_k)
    for (int t = 0; t < 16; ++t) {
        int rowl = 16 * wid + t;
        float v = lgs[rowl][lane];
        float vv = v; int ix = lane;
#pragma unroll
        for (int off = 32; off > 0; off >>= 1) {
            float ov = __shfl_down(vv, off, 64);
            int   oi = __shfl_down(ix, off, 64);
            if (ov > vv || (ov == vv && oi < ix)) { vv = ov; ix = oi; }
        }
        int   i1 = __shfl(ix, 0, 64);
        float v1 = __shfl(vv, 0, 64);

        vv = (lane == i1) ? -3.0e38f : v; ix = lane;
#pragma unroll
        for (int off = 32; off > 0; off >>= 1) {
            float ov = __shfl_down(vv, off, 64);
            int   oi = __shfl_down(ix, off, 64);
            if (ov > vv || (ov == vv && oi < ix)) { vv = ov; ix = oi; }
        }
        int   i2 = __shfl(ix, 0, 64);
        float v2 = __shfl(vv, 0, 64);

        if (lane == 0) {
            int n = t0 + rowl;
            double p0 = 1.0 / (1.0 + exp((double)(v2 - v1)));   // stable: v2 <= v1
            idx0[n] = i1;
            idx1[n] = i2;
            probs[2 * n]     = (float)p0;
            probs[2 * n + 1] = (float)(1.0 - p0);
            atomicAdd(&cnt[i1], 1);
            atomicAdd(&cnt[64 + i2], 1);
        }
    }

    __syncthreads();
    if (tid < 128) {
        int k = tid >> 6, e = tid & 63;
        gcounts[((size_t)k * gridDim.x + blockIdx.x) * 64 + e] = cnt[tid];
    }
}

// ---------------- K2: ranks (cross-segment prefix + intra-segment ballot) + mask + tail ----
__launch_bounds__(128)
__global__ void k_rank_out(const int* __restrict__ idx0, const int* __restrict__ idx1,
                           const int* __restrict__ gcounts, const float* __restrict__ probs,
                           float* __restrict__ out, int N, int cap, int nblk)
{
    const int b = blockIdx.x, tid = threadIdx.x;
    const int lane = tid & 63, kk = tid >> 6;   // wave 0: k=0, wave 1: k=1
    const int t0 = b * 64;
    __shared__ int sm_ix[2][64], sm_rk[2][64];

    const int v = (kk ? idx1 : idx0)[t0 + lane];

    // cross-segment base: counts of expert v in all earlier segments (deterministic)
    int base = 0;
    const int slim = kk * nblk + b;
    int s = 0;
    for (; s + 4 <= slim; s += 4)
        base += gcounts[(s + 0) * 64 + v] + gcounts[(s + 1) * 64 + v]
              + gcounts[(s + 2) * 64 + v] + gcounts[(s + 3) * 64 + v];
    for (; s < slim; ++s) base += gcounts[s * 64 + v];

    // intra-segment prefix via per-expert ballots (lane order == token order)
    const unsigned long long ltm = (1ull << lane) - 1ull;
    int pre = 0;
    for (int e = 0; e < 64; ++e) {
        unsigned long long bb = __ballot(v == e);
        if (v == e) pre = __popcll(bb & ltm);
    }
    const int rk = base + pre;
    sm_ix[kk][lane] = v;
    sm_rk[kk][lane] = rk;
    __syncthreads();

    // one-hot capacity mask rows for these 64 tokens: 2048 float4, 16/thread
#pragma unroll
    for (int rep = 0; rep < 16; ++rep) {
        int f   = tid + 128 * rep;
        int n2  = f >> 5;
        int rem = (f & 31) * 4;      // 0..124 within the token's 128 floats
        int kq  = rem >> 6;
        int e0  = rem & 63;
        int ix  = sm_ix[kq][n2];
        int rr  = sm_rk[kq][n2];
        float val = (rr < cap) ? 1.0f : 0.0f;
        float4 o = make_float4(0.f, 0.f, 0.f, 0.f);
        int d = ix - e0;
        if (d >= 0 && d < 4) ((float*)&o)[d] = val;
        *(float4*)(out + (size_t)(t0 + n2) * 128 + rem) = o;
    }

    // tail: probs_masked / indices / final_rank / capacity
    size_t B = (size_t)2 * N * E_DIM;
    {
        int n2 = tid >> 1, kq = tid & 1;
        int gi = 2 * (t0 + n2) + kq;
        int ix = sm_ix[kq][n2];
        int rr = sm_rk[kq][n2];
        bool keep = rr < cap;
        out[B + gi]         = keep ? probs[gi] : 0.0f;
        out[B + 2 * N + gi] = (float)ix;
        out[B + 4 * N + gi] = (float)rr;
    }
    if (b == 0 && tid == 0) out[B + 6 * N] = (float)cap;
}

extern "C" void kernel_launch(void* const* d_in, const int* in_sizes, int n_in,
                              void* d_out, int out_size, void* d_ws, size_t ws_size,
                              hipStream_t stream)
{
    const float* x  = (const float*)d_in[0];
    const float* wg = (const float*)d_in[1];
    const int N = in_sizes[0] / C_DIM;   // 16384 tokens
    const int nblk = N / BT;             // 256

    // workspace: idx0[N] idx1[N] probs[2N] gcounts[2*nblk*64] wh[64*2048 f16] wl[..] = 896 KB
    char* ws = (char*)d_ws;
    int*      idx0    = (int*)ws;
    int*      idx1    = idx0 + N;
    float*    probs   = (float*)(idx1 + N);
    int*      gcounts = (int*)(probs + 2 * N);
    _Float16* wh      = (_Float16*)(gcounts + 2 * nblk * 64);
    _Float16* wl      = wh + (size_t)E_DIM * C_DIM;

    float* out = (float*)d_out;

    int cap = (int)((long long)2 * 2 * N / E_DIM);   // TOP_K * EVAL_CAPACITY * N / E
    if (cap < 4) cap = 4;

    k_wsplit<<<(E_DIM * C_DIM / 4) / 256, 256, 0, stream>>>(wg, wh, wl);
    k_logits_top2<<<nblk, 256, 0, stream>>>(x, wh, wl, idx0, idx1, probs, gcounts, N);
    k_rank_out<<<nblk, 128, 0, stream>>>(idx0, idx1, gcounts, probs, out, N, cap, nblk);
}

// Round 4
// 251.340 us; speedup vs baseline: 1.8608x; 1.0878x over previous
//
#include <hip/hip_runtime.h>
#include <math.h>

#define C_DIM 2048
#define E_DIM 64
#define KC    128      // K dims per staged chunk
#define BT    16       // tokens per block
#define NW    4        // waves per block = K-split factor

typedef _Float16 h4    __attribute__((ext_vector_type(4)));
typedef _Float16 v8hf  __attribute__((ext_vector_type(8)));
typedef float    f32x4 __attribute__((ext_vector_type(4)));

#define SCALE      64.0f
#define INV_SCALE2 (1.0f/4096.0f)

// ---------------- K0: w -> fragment-ordered f16 (hi,lo), scaled x64 ----------------
// Layout: for K32-step q (0..63), expert-group ni (0..3), part (h=0,l=1): a 1 KB
// block of 64 lanes x 16 B. Lane l holds w[16ni+(l&15)][32q+(l>>4)*8 .. +8].
// B-frag loads in K1 become single fully-coalesced dwordx4 from L2.
__launch_bounds__(256)
__global__ void k_wsplit(const float* __restrict__ w, _Float16* __restrict__ wfrag)
{
    int t  = blockIdx.x * 256 + threadIdx.x;   // 0..16383
    int l  = t & 63;
    int ni = (t >> 6) & 3;
    int q  = t >> 8;
    int e  = 16 * ni + (l & 15);
    int k0 = 32 * q + (l >> 4) * 8;
    const float* src = w + (size_t)e * C_DIM + k0;
    float4 a = *(const float4*)(src);
    float4 b = *(const float4*)(src + 4);
    float s[8] = {a.x, a.y, a.z, a.w, b.x, b.y, b.z, b.w};
    v8hf hv, lv;
#pragma unroll
    for (int j = 0; j < 8; ++j) {
        float sc = s[j] * SCALE;
        _Float16 h = (_Float16)sc;          // RNE
        hv[j] = h;
        lv[j] = (_Float16)(sc - (float)h);  // Sterbenz-exact residual, then RNE
    }
    size_t fo = (size_t)(q * 4 + ni) * 2 * 512;   // f16 units (1 KB = 512 f16 per part)
    *(v8hf*)(wfrag + fo + l * 8)       = hv;
    *(v8hf*)(wfrag + fo + 512 + l * 8) = lv;
}

// ---------------- K1: MFMA logits (single fp32 acc, 3 products) + top-2 + histogram ----
// Block: 16 tokens x 64 experts, 4 waves = 4-way K-split (wave wk does K32-steps
// q = 4c+wk). x staged in LDS (f16 hi/lo, XOR swizzle (row&7)<<4); w frags read
// direct from fragment-ordered global (L2-resident). Deterministic LDS reduction
// over wk, then per-token top-2. Grid 1024 blocks -> 4 blocks/CU, 4 waves/SIMD.
__launch_bounds__(256, 4)
__global__ void k_logits_top2(const float* __restrict__ x, const _Float16* __restrict__ wfrag,
                              unsigned char* __restrict__ idx0, unsigned char* __restrict__ idx1,
                              float* __restrict__ dlt, unsigned short* __restrict__ gcounts,
                              int nblk)
{
    __shared__ alignas(16) char smem[2 * BT * KC * 2];   // xh[16][128] f16 + xl : 8 KB

    const int tid  = threadIdx.x;
    const int lane = tid & 63;
    const int wk   = tid >> 6;          // 0..3 : K-split index
    const int ln15 = lane & 15;
    const int g    = lane >> 4;
    const int t0   = blockIdx.x * BT;

    f32x4 acc[4];                        // experts 16ni..16ni+15
#pragma unroll
    for (int ni = 0; ni < 4; ++ni) acc[ni] = (f32x4)0.0f;

    float4 xr[2];

#define LOADX(kb)                                                              \
    {                                                                          \
        _Pragma("unroll")                                                      \
        for (int r = 0; r < 2; ++r) {                                          \
            int i = tid + 256 * r;                                             \
            int row = i >> 5, c4 = i & 31;                                     \
            xr[r] = *(const float4*)(x + (size_t)(t0 + row) * C_DIM + (kb) + c4 * 4); \
        }                                                                      \
    }

#define STOREX()                                                               \
    {                                                                          \
        _Pragma("unroll")                                                      \
        for (int r = 0; r < 2; ++r) {                                          \
            int i = tid + 256 * r;                                             \
            int row = i >> 5, c4 = i & 31;                                     \
            float4 v = xr[r];                                                  \
            float s0 = v.x * SCALE, s1 = v.y * SCALE, s2 = v.z * SCALE, s3 = v.w * SCALE; \
            _Float16 h0 = (_Float16)s0, h1 = (_Float16)s1, h2 = (_Float16)s2, h3 = (_Float16)s3; \
            h4 hv = {h0, h1, h2, h3};                                          \
            h4 lv = {(_Float16)(s0 - (float)h0), (_Float16)(s1 - (float)h1),   \
                     (_Float16)(s2 - (float)h2), (_Float16)(s3 - (float)h3)};  \
            int boff = row * 256 + ((c4 * 8) ^ ((row & 7) << 4));              \
            *(h4*)(smem + boff) = hv;                                          \
            *(h4*)(smem + 4096 + boff) = lv;                                   \
        }                                                                      \
    }

    // prologue: stage chunk 0
    LOADX(0);
    STOREX();
    __syncthreads();

    const int aoff = ln15 * 256 + (((wk << 6) + (g << 4)) ^ ((ln15 & 7) << 4));

    for (int c = 0; c < 16; ++c) {
        if (c < 15) LOADX((c + 1) * KC);   // prefetch next x chunk into regs (T14)

        // B-frags: direct coalesced global loads (L2-resident), q = 4c + wk
        const char* wp = (const char*)wfrag + ((size_t)(4 * c + wk) << 13) + (lane << 4);
        v8hf bh[4], bl[4];
#pragma unroll
        for (int ni = 0; ni < 4; ++ni) {
            bh[ni] = *(const v8hf*)(wp + (size_t)(2 * ni) * 1024);
            bl[ni] = *(const v8hf*)(wp + (size_t)(2 * ni) * 1024 + 1024);
        }
        // A-frags from LDS (hi, lo)
        v8hf ah = *(const v8hf*)(smem + aoff);
        v8hf al = *(const v8hf*)(smem + 4096 + aoff);

#pragma unroll
        for (int ni = 0; ni < 4; ++ni) {
            acc[ni] = __builtin_amdgcn_mfma_f32_16x16x32_f16(ah, bh[ni], acc[ni], 0, 0, 0);
            acc[ni] = __builtin_amdgcn_mfma_f32_16x16x32_f16(ah, bl[ni], acc[ni], 0, 0, 0);
            acc[ni] = __builtin_amdgcn_mfma_f32_16x16x32_f16(al, bh[ni], acc[ni], 0, 0, 0);
        }

        __syncthreads();                  // all waves done reading chunk c
        if (c < 15) STOREX();             // stage chunk c+1
        __syncthreads();
    }

    // ---- deterministic K-split reduction into lgs[16][64] (reuses smem) ----
    float* lgs = (float*)smem;            // 4 KB
    int*   cnt = (int*)(smem + 4096);     // 512 B
    if (tid < 128) cnt[tid] = 0;
#pragma unroll
    for (int w = 0; w < NW; ++w) {
        if (wk == w) {
#pragma unroll
            for (int ni = 0; ni < 4; ++ni)
#pragma unroll
                for (int gg = 0; gg < 4; ++gg) {
                    int row = (g << 2) + gg;          // C/D: row=(l>>4)*4+reg
                    int e   = 16 * ni + ln15;         // col=l&15 within tile ni
                    float vv = acc[ni][gg] * INV_SCALE2;
                    if (w == 0) lgs[row * 64 + e]  = vv;
                    else        lgs[row * 64 + e] += vv;
                }
        }
        __syncthreads();
    }

    // ---- per-token top-2 (lane == expert), lower index wins ties ----
#pragma unroll
    for (int t = 0; t < 4; ++t) {
        int rowl = (wk << 2) + t;
        float v = lgs[rowl * 64 + lane];
        float vv = v; int ix = lane;
#pragma unroll
        for (int off = 32; off > 0; off >>= 1) {
            float ov = __shfl_down(vv, off, 64);
            int   oi = __shfl_down(ix, off, 64);
            if (ov > vv || (ov == vv && oi < ix)) { vv = ov; ix = oi; }
        }
        int   i1 = __shfl(ix, 0, 64);
        float v1 = __shfl(vv, 0, 64);

        vv = (lane == i1) ? -3.0e38f : v; ix = lane;
#pragma unroll
        for (int off = 32; off > 0; off >>= 1) {
            float ov = __shfl_down(vv, off, 64);
            int   oi = __shfl_down(ix, off, 64);
            if (ov > vv || (ov == vv && oi < ix)) { vv = ov; ix = oi; }
        }
        int   i2 = __shfl(ix, 0, 64);
        float v2 = __shfl(vv, 0, 64);

        if (lane == 0) {
            int n = t0 + rowl;
            idx0[n] = (unsigned char)i1;
            idx1[n] = (unsigned char)i2;
            dlt[n]  = v2 - v1;             // probs recomputed in k_rank_out (f32, = jax softmax)
            atomicAdd(&cnt[i1], 1);
            atomicAdd(&cnt[64 + i2], 1);
        }
    }

    __syncthreads();
    if (tid < 128) {
        int e = tid & 63, k = tid >> 6;    // segment s = k*nblk + block (k-major = rank order)
        gcounts[(size_t)e * (2 * nblk) + k * nblk + blockIdx.x] = (unsigned short)cnt[tid];
    }
}

// ---------------- K2: in-place exclusive prefix over segments, per expert ----------------
// Replaces rank_out's O(nblk) per-lane gather loop with one precomputed value.
__launch_bounds__(64)
__global__ void k_scan2(unsigned short* __restrict__ g, int S)
{
    const int e = blockIdx.x, lane = threadIdx.x;
    unsigned short* row = g + (size_t)e * S;
    int vals[32];                          // S = 2048 -> 32 rounds of 64
    const int R = S >> 6;
#pragma unroll
    for (int r = 0; r < 32; ++r) if (r < R) vals[r] = row[(r << 6) + lane];
    int running = 0;
#pragma unroll
    for (int r = 0; r < 32; ++r) {
        if (r >= R) break;
        int v = vals[r], s = v;
#pragma unroll
        for (int off = 1; off < 64; off <<= 1) {
            int t = __shfl_up(s, off, 64);
            if (lane >= off) s += t;
        }
        row[(r << 6) + lane] = (unsigned short)(s - v + running);   // exclusive + carry
        running += __shfl(s, 63, 64);
    }
}

// ---------------- K3: ranks (1 prefix load + ballot) + mask + tail ----------------
__launch_bounds__(128)
__global__ void k_rank_out(const unsigned char* __restrict__ idx0, const unsigned char* __restrict__ idx1,
                           const unsigned short* __restrict__ gpre, const float* __restrict__ dlt,
                           float* __restrict__ out, int N, int cap, int nblk)
{
    const int b = blockIdx.x, tid = threadIdx.x;
    const int lane = tid & 63, kk = tid >> 6;   // wave 0: k=0, wave 1: k=1
    const int t0 = b * BT;
    __shared__ int sm_ix[2][BT], sm_rk[2][BT];

    int v = -1, base = 0;
    if (lane < BT) {
        v = (kk ? idx1 : idx0)[t0 + lane];
        base = gpre[(size_t)v * (2 * nblk) + kk * nblk + b];   // exclusive prefix over earlier segments
    }
    const unsigned long long ltm = (1ull << lane) - 1ull;
    int pre = 0;
    for (int e = 0; e < 64; ++e) {
        unsigned long long bb = __ballot(v == e);
        if (v == e) pre = __popcll(bb & ltm);
    }
    if (lane < BT) { sm_ix[kk][lane] = v; sm_rk[kk][lane] = base + pre; }
    __syncthreads();

    // one-hot capacity mask: 16 tokens x 128 floats = 512 float4, 4/thread
#pragma unroll
    for (int rep = 0; rep < 4; ++rep) {
        int f   = tid + 128 * rep;
        int n2  = f >> 5;
        int rem = (f & 31) * 4;
        int kq  = rem >> 6;
        int e0  = rem & 63;
        int ix  = sm_ix[kq][n2];
        int rr  = sm_rk[kq][n2];
        float val = (rr < cap) ? 1.0f : 0.0f;
        float4 o = make_float4(0.f, 0.f, 0.f, 0.f);
        int d = ix - e0;
        if (d >= 0 && d < 4) ((float*)&o)[d] = val;
        *(float4*)(out + (size_t)(t0 + n2) * 128 + rem) = o;
    }

    // tail: probs_masked / indices / final_rank / capacity
    size_t B = (size_t)2 * N * E_DIM;
    if (tid < 2 * BT) {
        int n2 = tid >> 1, kq = tid & 1;
        int n  = t0 + n2;
        int gi = 2 * n + kq;
        int ix = sm_ix[kq][n2];
        int rr = sm_rk[kq][n2];
        float d  = dlt[n];                  // v2 - v1 (<= 0)
        float e1 = expf(d);
        float inv = 1.0f / (1.0f + e1);     // = jax f32 softmax([v1,v2])
        float p  = kq ? (e1 * inv) : inv;
        bool keep = rr < cap;
        out[B + gi]         = keep ? p : 0.0f;
        out[B + 2 * N + gi] = (float)ix;
        out[B + 4 * N + gi] = (float)rr;
    }
    if (b == 0 && tid == 0) out[B + 6 * N] = (float)cap;
}

extern "C" void kernel_launch(void* const* d_in, const int* in_sizes, int n_in,
                              void* d_out, int out_size, void* d_ws, size_t ws_size,
                              hipStream_t stream)
{
    const float* x  = (const float*)d_in[0];
    const float* wg = (const float*)d_in[1];
    const int N = in_sizes[0] / C_DIM;   // 16384 tokens
    const int nblk = N / BT;             // 1024

    // workspace: idx0[N]u8 idx1[N]u8 dlt[N]f32 gcounts[64][2*nblk]u16 wfrag 512K = 864 KB
    char* ws = (char*)d_ws;
    unsigned char*  idx0    = (unsigned char*)ws;
    unsigned char*  idx1    = idx0 + N;
    float*          dlt     = (float*)(idx1 + N);
    unsigned short* gcounts = (unsigned short*)(dlt + N);
    _Float16*       wfrag   = (_Float16*)(gcounts + (size_t)64 * 2 * nblk);

    float* out = (float*)d_out;

    int cap = (int)((long long)2 * 2 * N / E_DIM);   // TOP_K * EVAL_CAPACITY * N / E
    if (cap < 4) cap = 4;

    k_wsplit<<<64, 256, 0, stream>>>(wg, wfrag);
    k_logits_top2<<<nblk, 256, 0, stream>>>(x, wfrag, idx0, idx1, dlt, gcounts, nblk);
    k_scan2<<<E_DIM, 64, 0, stream>>>(gcounts, 2 * nblk);
    k_rank_out<<<nblk, 128, 0, stream>>>(idx0, idx1, gcounts, dlt, out, N, cap, nblk);
}

// Round 5
// 240.790 us; speedup vs baseline: 1.9423x; 1.0438x over previous
//
#include <hip/hip_runtime.h>
#include <math.h>

#define C_DIM 2048
#define E_DIM 64
#define KC    128      // K dims per staged chunk
#define BT    32       // tokens per block (= M per wave; 2 row-tiles)
#define NW    4        // waves per block = K-split factor

typedef _Float16 h4    __attribute__((ext_vector_type(4)));
typedef _Float16 v8hf  __attribute__((ext_vector_type(8)));
typedef float    f32x4 __attribute__((ext_vector_type(4)));

#define SCALE      64.0f
#define INV_SCALE2 (1.0f/4096.0f)

// ---------------- K0: w -> fragment-ordered f16 (hi,lo), scaled x64 ----------------
// For K32-step q (0..63), expert-group ni (0..3): 2 KB block = hi(1 KB) + lo(1 KB),
// each 64 lanes x 16 B. Lane l holds w[16ni+(l&15)][32q+(l>>4)*8 .. +8].
__launch_bounds__(256)
__global__ void k_wsplit(const float* __restrict__ w, _Float16* __restrict__ wfrag)
{
    int t  = blockIdx.x * 256 + threadIdx.x;   // 0..16383
    int l  = t & 63;
    int ni = (t >> 6) & 3;
    int q  = t >> 8;
    int e  = 16 * ni + (l & 15);
    int k0 = 32 * q + (l >> 4) * 8;
    const float* src = w + (size_t)e * C_DIM + k0;
    float4 a = *(const float4*)(src);
    float4 b = *(const float4*)(src + 4);
    float s[8] = {a.x, a.y, a.z, a.w, b.x, b.y, b.z, b.w};
    v8hf hv, lv;
#pragma unroll
    for (int j = 0; j < 8; ++j) {
        float sc = s[j] * SCALE;
        _Float16 h = (_Float16)sc;          // RNE
        hv[j] = h;
        lv[j] = (_Float16)(sc - (float)h);  // Sterbenz-exact residual, then RNE
    }
    size_t fo = (size_t)(q * 4 + ni) * 1024;   // f16 units: 1024 f16 = 2 KB per (q,ni)
    *(v8hf*)(wfrag + fo + l * 8)       = hv;
    *(v8hf*)(wfrag + fo + 512 + l * 8) = lv;
}

// ---------------- K1: MFMA logits + top-2 + histogram ----------------
// Block: 32 tokens x 64 experts, 4 waves = 4-way K-split. Wave wk handles
// K32-step q = 4c+wk of chunk c; M/wave = 32 (2 row-tiles) so B-frag L2 traffic
// halves vs M=16. x staged f16-split in double-buffered swizzled LDS (1 barrier
// per chunk); B frags register-prefetched one chunk ahead (L2 latency hidden).
// Single fp32 acc for hh+hl+lh products; logit err ~1e-6 (passes at absmax 2e-3).
__launch_bounds__(256)
__global__ void k_logits_top2(const float* __restrict__ x, const _Float16* __restrict__ wfrag,
                              unsigned char* __restrict__ idx0, unsigned char* __restrict__ idx1,
                              float* __restrict__ dlt, unsigned short* __restrict__ gcounts,
                              int nblk)
{
    __shared__ alignas(16) char smem[2 * 16384];   // [buf][part(hi/lo)][32 rows][256 B] = 32 KB

    const int tid  = threadIdx.x;
    const int lane = tid & 63;
    const int wk   = tid >> 6;          // 0..3 : K-split index
    const int ln15 = lane & 15;
    const int g    = lane >> 4;
    const int t0   = blockIdx.x * BT;

    f32x4 acc[2][4];
#pragma unroll
    for (int mi = 0; mi < 2; ++mi)
#pragma unroll
        for (int ni = 0; ni < 4; ++ni) acc[mi][ni] = (f32x4)0.0f;

    float4 xr[4];
    v8hf bh[2][4], bl[2][4];            // [c&1][ni] — static indices under full unroll

#define LOADX(kb)                                                               \
    {                                                                           \
        _Pragma("unroll")                                                       \
        for (int r = 0; r < 4; ++r) {                                           \
            int i = tid + 256 * r;                                              \
            int row = i >> 5, c4 = i & 31;                                      \
            xr[r] = *(const float4*)(x + (size_t)(t0 + row) * C_DIM + (kb) + c4 * 4); \
        }                                                                       \
    }

#define STOREX(bf)                                                              \
    {                                                                           \
        _Pragma("unroll")                                                       \
        for (int r = 0; r < 4; ++r) {                                           \
            int i = tid + 256 * r;                                              \
            int row = i >> 5, c4 = i & 31;                                      \
            float4 v = xr[r];                                                   \
            float s0 = v.x * SCALE, s1 = v.y * SCALE, s2 = v.z * SCALE, s3 = v.w * SCALE; \
            _Float16 h0 = (_Float16)s0, h1 = (_Float16)s1, h2 = (_Float16)s2, h3 = (_Float16)s3; \
            h4 hv = {h0, h1, h2, h3};                                           \
            h4 lv = {(_Float16)(s0 - (float)h0), (_Float16)(s1 - (float)h1),    \
                     (_Float16)(s2 - (float)h2), (_Float16)(s3 - (float)h3)};   \
            int boff = (bf) * 16384 + row * 256 + ((c4 * 8) ^ ((row & 7) << 4));\
            *(h4*)(smem + boff)        = hv;                                    \
            *(h4*)(smem + boff + 8192) = lv;                                    \
        }                                                                       \
    }

#define LOADB(c, s)                                                             \
    {                                                                           \
        const char* wp = (const char*)wfrag + ((size_t)(4 * (c) + wk) << 13) + (lane << 4); \
        _Pragma("unroll")                                                       \
        for (int ni = 0; ni < 4; ++ni) {                                        \
            bh[s][ni] = *(const v8hf*)(wp + ni * 2048);                         \
            bl[s][ni] = *(const v8hf*)(wp + ni * 2048 + 1024);                  \
        }                                                                       \
    }

    // prologue: chunk 0 staged, B(0) in regs
    LOADX(0);
    LOADB(0, 0);
    STOREX(0);
    __syncthreads();

    const int sw   = (ln15 & 7) << 4;
    const int koff = ((wk << 6) + (g << 4)) ^ sw;

#pragma unroll
    for (int c = 0; c < 16; ++c) {
        const int cur = c & 1, nxt = cur ^ 1;
        if (c < 15) {
            LOADX((c + 1) * KC);        // x prefetch (HBM) -> regs
            LOADB(c + 1, nxt);          // B prefetch (L2) -> regs
        }
        // A-frags from LDS buffer cur
        v8hf ah[2], al[2];
#pragma unroll
        for (int mi = 0; mi < 2; ++mi) {
            int ro = cur * 16384 + (16 * mi + ln15) * 256 + koff;
            ah[mi] = *(const v8hf*)(smem + ro);
            al[mi] = *(const v8hf*)(smem + ro + 8192);
        }
#pragma unroll
        for (int ni = 0; ni < 4; ++ni)
#pragma unroll
            for (int mi = 0; mi < 2; ++mi) {
                acc[mi][ni] = __builtin_amdgcn_mfma_f32_16x16x32_f16(ah[mi], bh[cur][ni], acc[mi][ni], 0, 0, 0);
                acc[mi][ni] = __builtin_amdgcn_mfma_f32_16x16x32_f16(ah[mi], bl[cur][ni], acc[mi][ni], 0, 0, 0);
                acc[mi][ni] = __builtin_amdgcn_mfma_f32_16x16x32_f16(al[mi], bh[cur][ni], acc[mi][ni], 0, 0, 0);
            }
        if (c < 15) STOREX(nxt);        // waits x; writes the buffer freed at prev barrier
        __syncthreads();
    }

    // ---- deterministic K-split reduction into lgs[32][64] (reuses smem) ----
    float* lgs = (float*)smem;              // 8 KB
    int*   cnt = (int*)(smem + 8192);       // 512 B
    if (tid < 128) cnt[tid] = 0;
#pragma unroll
    for (int w = 0; w < NW; ++w) {
        if (wk == w) {
#pragma unroll
            for (int mi = 0; mi < 2; ++mi)
#pragma unroll
                for (int ni = 0; ni < 4; ++ni)
#pragma unroll
                    for (int gg = 0; gg < 4; ++gg) {
                        int row = 16 * mi + (g << 2) + gg;    // C/D: row=(l>>4)*4+reg
                        int e   = 16 * ni + ln15;             // col=l&15
                        float vv = acc[mi][ni][gg] * INV_SCALE2;
                        if (w == 0) lgs[row * 64 + e]  = vv;
                        else        lgs[row * 64 + e] += vv;
                    }
        }
        __syncthreads();
    }

    // ---- per-token top-2 (lane == expert), lower index wins ties ----
#pragma unroll
    for (int t = 0; t < 8; ++t) {
        int rowl = (wk << 3) + t;
        float v = lgs[rowl * 64 + lane];
        float vv = v; int ix = lane;
#pragma unroll
        for (int off = 32; off > 0; off >>= 1) {
            float ov = __shfl_down(vv, off, 64);
            int   oi = __shfl_down(ix, off, 64);
            if (ov > vv || (ov == vv && oi < ix)) { vv = ov; ix = oi; }
        }
        int   i1 = __shfl(ix, 0, 64);
        float v1 = __shfl(vv, 0, 64);

        vv = (lane == i1) ? -3.0e38f : v; ix = lane;
#pragma unroll
        for (int off = 32; off > 0; off >>= 1) {
            float ov = __shfl_down(vv, off, 64);
            int   oi = __shfl_down(ix, off, 64);
            if (ov > vv || (ov == vv && oi < ix)) { vv = ov; ix = oi; }
        }
        int   i2 = __shfl(ix, 0, 64);
        float v2 = __shfl(vv, 0, 64);

        if (lane == 0) {
            int n = t0 + rowl;
            idx0[n] = (unsigned char)i1;
            idx1[n] = (unsigned char)i2;
            dlt[n]  = v2 - v1;             // probs recomputed in k_rank_out
            atomicAdd(&cnt[i1], 1);
            atomicAdd(&cnt[64 + i2], 1);
        }
    }

    __syncthreads();
    if (tid < 128) {
        int e = tid & 63, k = tid >> 6;    // segment s = k*nblk + block (k-major = rank order)
        gcounts[(size_t)e * (2 * nblk) + k * nblk + blockIdx.x] = (unsigned short)cnt[tid];
    }
}

// ---------------- K2: in-place exclusive prefix over segments, per expert ----------------
__launch_bounds__(64)
__global__ void k_scan2(unsigned short* __restrict__ g, int S)
{
    const int e = blockIdx.x, lane = threadIdx.x;
    unsigned short* row = g + (size_t)e * S;
    int vals[16];                          // S = 1024 -> 16 rounds of 64
    const int R = S >> 6;
#pragma unroll
    for (int r = 0; r < 16; ++r) if (r < R) vals[r] = row[(r << 6) + lane];
    int running = 0;
#pragma unroll
    for (int r = 0; r < 16; ++r) {
        if (r >= R) break;
        int v = vals[r], s = v;
#pragma unroll
        for (int off = 1; off < 64; off <<= 1) {
            int t = __shfl_up(s, off, 64);
            if (lane >= off) s += t;
        }
        row[(r << 6) + lane] = (unsigned short)(s - v + running);   // exclusive + carry
        running += __shfl(s, 63, 64);
    }
}

// ---------------- K3: ranks (1 prefix load + ballot) + mask + tail ----------------
__launch_bounds__(128)
__global__ void k_rank_out(const unsigned char* __restrict__ idx0, const unsigned char* __restrict__ idx1,
                           const unsigned short* __restrict__ gpre, const float* __restrict__ dlt,
                           float* __restrict__ out, int N, int cap, int nblk)
{
    const int b = blockIdx.x, tid = threadIdx.x;
    const int lane = tid & 63, kk = tid >> 6;   // wave 0: k=0, wave 1: k=1
    const int t0 = b * BT;
    __shared__ int sm_ix[2][BT], sm_rk[2][BT];

    int v = -1, base = 0;
    if (lane < BT) {
        v = (kk ? idx1 : idx0)[t0 + lane];
        base = gpre[(size_t)v * (2 * nblk) + kk * nblk + b];   // exclusive prefix of earlier segments
    }
    const unsigned long long ltm = (1ull << lane) - 1ull;
    int pre = 0;
    for (int e = 0; e < 64; ++e) {
        unsigned long long bb = __ballot(v == e);
        if (v == e) pre = __popcll(bb & ltm);
    }
    if (lane < BT) { sm_ix[kk][lane] = v; sm_rk[kk][lane] = base + pre; }
    __syncthreads();

    // one-hot capacity mask: 32 tokens x 128 floats = 1024 float4, 8/thread
#pragma unroll
    for (int rep = 0; rep < 8; ++rep) {
        int f   = tid + 128 * rep;
        int n2  = f >> 5;
        int rem = (f & 31) * 4;
        int kq  = rem >> 6;
        int e0  = rem & 63;
        int ix  = sm_ix[kq][n2];
        int rr  = sm_rk[kq][n2];
        float val = (rr < cap) ? 1.0f : 0.0f;
        float4 o = make_float4(0.f, 0.f, 0.f, 0.f);
        int d = ix - e0;
        if (d >= 0 && d < 4) ((float*)&o)[d] = val;
        *(float4*)(out + (size_t)(t0 + n2) * 128 + rem) = o;
    }

    // tail: probs_masked / indices / final_rank / capacity
    size_t B = (size_t)2 * N * E_DIM;
    if (tid < 2 * BT) {
        int n2 = tid >> 1, kq = tid & 1;
        int n  = t0 + n2;
        int gi = 2 * n + kq;
        int ix = sm_ix[kq][n2];
        int rr = sm_rk[kq][n2];
        float d  = dlt[n];                  // v2 - v1 (<= 0)
        float e1 = expf(d);
        float inv = 1.0f / (1.0f + e1);     // = jax f32 softmax([v1,v2])
        float p  = kq ? (e1 * inv) : inv;
        bool keep = rr < cap;
        out[B + gi]         = keep ? p : 0.0f;
        out[B + 2 * N + gi] = (float)ix;
        out[B + 4 * N + gi] = (float)rr;
    }
    if (b == 0 && tid == 0) out[B + 6 * N] = (float)cap;
}

extern "C" void kernel_launch(void* const* d_in, const int* in_sizes, int n_in,
                              void* d_out, int out_size, void* d_ws, size_t ws_size,
                              hipStream_t stream)
{
    const float* x  = (const float*)d_in[0];
    const float* wg = (const float*)d_in[1];
    const int N = in_sizes[0] / C_DIM;   // 16384 tokens
    const int nblk = N / BT;             // 512

    // workspace: idx0[N]u8 idx1[N]u8 dlt[N]f32 gcounts[64][2*nblk]u16 wfrag[256K f16] = 736 KB
    char* ws = (char*)d_ws;
    unsigned char*  idx0    = (unsigned char*)ws;
    unsigned char*  idx1    = idx0 + N;
    float*          dlt     = (float*)(idx1 + N);
    unsigned short* gcounts = (unsigned short*)(dlt + N);
    _Float16*       wfrag   = (_Float16*)(gcounts + (size_t)64 * 2 * nblk);

    float* out = (float*)d_out;

    int cap = (int)((long long)2 * 2 * N / E_DIM);   // TOP_K * EVAL_CAPACITY * N / E
    if (cap < 4) cap = 4;

    k_wsplit<<<64, 256, 0, stream>>>(wg, wfrag);
    k_logits_top2<<<nblk, 256, 0, stream>>>(x, wfrag, idx0, idx1, dlt, gcounts, nblk);
    k_scan2<<<E_DIM, 64, 0, stream>>>(gcounts, 2 * nblk);
    k_rank_out<<<nblk, 128, 0, stream>>>(idx0, idx1, gcounts, dlt, out, N, cap, nblk);
}